// Round 3
// baseline (101.556 us; speedup 1.0000x reference)
//
#include <hip/hip_runtime.h>

#define SCALE 8
#define N_ 8
#define C_ 48
#define H_ 48
#define W_ 64
#define WT 16            // w-tile width
#define HO (H_*SCALE)    // 384
#define WO (W_*SCALE)    // 512

typedef float f32x2 __attribute__((ext_vector_type(2)));
typedef float f32x4 __attribute__((ext_vector_type(4)));

// out[n][c][h*8+p][w*8+q] = sum_k softmax_k(mask[n][k*64+p*8+q][h][w]) * inp_pad[n][c][h+di-1][w+dj-1]
// k = di*3+dj (row-major 3x3 taps, zero padding)
__global__ __launch_bounds__(256, 3) void raft_up_kernel(
    const float* __restrict__ inp, const float* __restrict__ mask,
    float* __restrict__ out)
{
    // weights: 4 sub-arrays [qq2=q>>1][k][p][wi] of float2 (component = q&1)
    // flat float index: (((qq2*9 + k)*8 + p)*16 + wi)*2 + (q&1)
    __shared__ float wgt[4 * 9 * 8 * 16 * 2];   // 36.9 KB
    __shared__ float tin[C_ * 3 * (WT + 2)];    // 10.1 KB  [c][di][j]

    const int t = threadIdx.x;
    const int bid = blockIdx.x;
    const int wblk = bid % (W_ / WT);
    const int h = (bid / (W_ / WT)) % H_;
    const int n = bid / ((W_ / WT) * H_);
    const int w0 = wblk * WT;

    // ---- Phase 0: stage input halo tile: tin[c][di][j] = inp[n][c][h+di-1][w0-1+j]
    for (int e = t; e < C_ * 3 * (WT + 2); e += 256) {
        int c   = e / (3 * (WT + 2));
        int rem = e % (3 * (WT + 2));
        int di  = rem / (WT + 2);
        int j   = rem % (WT + 2);
        int row = h + di - 1;
        int col = w0 - 1 + j;
        float v = 0.f;
        if (row >= 0 && row < H_ && col >= 0 && col < W_)
            v = inp[(((size_t)n * C_ + c) * H_ + row) * W_ + col];
        tin[e] = v;
    }

    // ---- Phase 1: softmax over 9 taps -> LDS weights (wi fastest across lanes: coalesced mask reads)
    #pragma unroll
    for (int r = 0; r < (64 * WT) / 256; ++r) {
        int id = r * 256 + t;
        int wi = id & (WT - 1);
        int sp = id / WT;            // p*8 + q
        int p  = sp >> 3, q = sp & 7;
        const float* mp = mask + (size_t)n * 576 * H_ * W_
                               + (size_t)sp * H_ * W_
                               + (size_t)h * W_ + w0 + wi;
        float v[9];
        float mx = -1e30f;
        #pragma unroll
        for (int k = 0; k < 9; ++k) {
            float x = __builtin_nontemporal_load(&mp[(size_t)k * 64 * H_ * W_]);
            v[k] = x;
            mx = fmaxf(mx, x);
        }
        float s = 0.f;
        #pragma unroll
        for (int k = 0; k < 9; ++k) { v[k] = __expf(v[k] - mx); s += v[k]; }
        float inv = 1.f / s;
        #pragma unroll
        for (int k = 0; k < 9; ++k)
            wgt[((((q >> 1) * 9 + k) * 8 + p) * 16 + wi) * 2 + (q & 1)] = v[k] * inv;
    }
    __syncthreads();

    // ---- Phase 2: thread owns (qq, wi) = 4 consecutive output columns; 6 channels each
    const int lane5 = t & 31;
    const int qq = lane5 & 1;        // 0 -> q 0..3, 1 -> q 4..7
    const int wi = lane5 >> 1;       // 0..15
    const int cg = t >> 5;           // 0..7
    const int c0 = cg * 6;

    // taps for my 6 channels, loaded once (broadcast-friendly: address depends only on wi)
    float taps[6][9];
    #pragma unroll
    for (int cc = 0; cc < 6; ++cc)
        #pragma unroll
        for (int di = 0; di < 3; ++di)
            #pragma unroll
            for (int dj = 0; dj < 3; ++dj)
                taps[cc][di * 3 + dj] = tin[((c0 + cc) * 3 + di) * (WT + 2) + wi + dj];

    float* outb = out + (((size_t)n * C_ + c0) * HO + (size_t)h * SCALE) * WO
                      + (size_t)w0 * SCALE + wi * 8 + qq * 4;

    #pragma unroll
    for (int p = 0; p < 8; ++p) {
        // weights for my 4 q's, all 9 taps: 18 x ds_read_b64
        f32x4 w4[9];
        #pragma unroll
        for (int k = 0; k < 9; ++k) {
            f32x2 av = *(const f32x2*)&wgt[(((qq * 2 + 0) * 9 + k) * 8 + p) * 32 + wi * 2];
            f32x2 bv = *(const f32x2*)&wgt[(((qq * 2 + 1) * 9 + k) * 8 + p) * 32 + wi * 2];
            w4[k] = (f32x4){av.x, av.y, bv.x, bv.y};
        }
        #pragma unroll
        for (int cc = 0; cc < 6; ++cc) {
            f32x4 acc = (f32x4){0.f, 0.f, 0.f, 0.f};
            #pragma unroll
            for (int k = 0; k < 9; ++k) {
                float tp = taps[cc][k];
                acc.x = fmaf(w4[k].x, tp, acc.x);
                acc.y = fmaf(w4[k].y, tp, acc.y);
                acc.z = fmaf(w4[k].z, tp, acc.z);
                acc.w = fmaf(w4[k].w, tp, acc.w);
            }
            __builtin_nontemporal_store(acc, (f32x4*)(outb + ((size_t)cc * HO + p) * WO));
        }
    }
}

extern "C" void kernel_launch(void* const* d_in, const int* in_sizes, int n_in,
                              void* d_out, int out_size, void* d_ws, size_t ws_size,
                              hipStream_t stream) {
    const float* inp  = (const float*)d_in[0];
    const float* mask = (const float*)d_in[1];
    float* out = (float*)d_out;
    const int blocks = N_ * H_ * (W_ / WT);  // 8*48*4 = 1536
    raft_up_kernel<<<blocks, 256, 0, stream>>>(inp, mask, out);
}